// Round 14
// baseline (289.398 us; speedup 1.0000x reference)
//
#include <hip/hip_runtime.h>

#define L 21
#define C0 32
#define C1 32
#define IN_DIM 7
#define GHIST 256
#define BPAD 256  // bucket padding -> every 256-slot chunk is layer-uniform

// ---------------- K1: per-block histogram of idx ----------------
__global__ __launch_bounds__(256) void k_hist(const int* __restrict__ idx, int E,
                                              int* __restrict__ blockCounts) {
  __shared__ int h[L];
  int tid = threadIdx.x;
  if (tid < L) h[tid] = 0;
  __syncthreads();
  int per = (E + GHIST - 1) / GHIST;
  int s = blockIdx.x * per;
  int e = min(E, s + per);
  for (int i = s + tid; i < e; i += blockDim.x)
    atomicAdd(&h[idx[i]], 1);
  __syncthreads();
  if (tid < L) blockCounts[blockIdx.x * L + tid] = h[tid];
}

// ---------------- K2: totals, 256-padded bases, per-block cursors -------------
__global__ __launch_bounds__(256) void k_scan(const int* __restrict__ blockCounts,
                                              int* __restrict__ cursor,
                                              int* __restrict__ endArr,
                                              int* __restrict__ baseArr) {
  __shared__ int tot[L];
  __shared__ int base[L + 1];
  int tid = threadIdx.x;
  if (tid < L) {
    int s = 0;
#pragma unroll 8
    for (int b = 0; b < GHIST; b++) s += blockCounts[b * L + tid];
    tot[tid] = s;
  }
  __syncthreads();
  if (tid == 0) {
    int a = 0;
    for (int l = 0; l < L; l++) { base[l] = a; a += (tot[l] + BPAD - 1) & ~(BPAD - 1); }
    base[L] = a;
  }
  __syncthreads();
  if (tid < L) {
    int a = base[tid];
#pragma unroll 8
    for (int b = 0; b < GHIST; b++) {
      cursor[b * L + tid] = a;
      a += blockCounts[b * L + tid];
    }
    endArr[tid] = base[tid] + tot[tid];
  }
  if (tid <= L) baseArr[tid] = base[tid];
}

// ---------------- K3: scatter edge ids + gather input rows (fused) ------------
__global__ __launch_bounds__(256) void k_scatter(const int* __restrict__ idx,
                                                 const float* __restrict__ inp, int E,
                                                 const int* __restrict__ cursor,
                                                 int* __restrict__ perm,
                                                 float* __restrict__ xb) {
  __shared__ int cur[L];
  int tid = threadIdx.x;
  if (tid < L) cur[tid] = cursor[blockIdx.x * L + tid];
  __syncthreads();
  int per = (E + GHIST - 1) / GHIST;
  int s = blockIdx.x * per;
  int e = min(E, s + per);
  for (int i = s + tid; i < e; i += blockDim.x) {
    int l = idx[i];
    int pos = atomicAdd(&cur[l], 1);
    perm[pos] = i;
    const float* row = inp + (size_t)i * IN_DIM;
    float4 a, b;
    a.x = row[0]; a.y = row[1]; a.z = row[2]; a.w = row[3];
    b.x = row[4]; b.y = row[5]; b.z = row[6]; b.w = 0.f;
    float4* dst = (float4*)(xb + (size_t)pos * 8);
    dst[0] = a;
    dst[1] = b;
  }
}

// ---------------- K4 (PRODUCTION, R6 exact): block-uniform l, scalar weights,
// barrier-free per-wave LDS transpose epilogue, perm-scattered stores to out.
__global__ __launch_bounds__(256) void k_compute(const float* __restrict__ xb,
                                                 const float* __restrict__ W0g,
                                                 const float* __restrict__ b0g,
                                                 const float* __restrict__ W1g,
                                                 const float* __restrict__ b1g,
                                                 const int* __restrict__ perm,
                                                 const int* __restrict__ baseArr,
                                                 const int* __restrict__ endArr,
                                                 float* __restrict__ out) {
  int T = threadIdx.x;
  int lane = T & 63;
  int blockbase = blockIdx.x << 8;

  int bv = baseArr[lane <= L ? lane : L];
  unsigned long long m = __ballot((lane <= L) && (blockbase >= bv));
  int l = __popcll(m) - 1;
  if (l >= L) return;
  l = __builtin_amdgcn_readfirstlane(l);
  int end = __builtin_amdgcn_readfirstlane(endArr[l]);

  int slot = blockbase + T;
  const float4* xrow = (const float4*)(xb + (size_t)slot * 8);
  float4 xa = xrow[0], xc = xrow[1];
  float x[IN_DIM] = {xa.x, xa.y, xa.z, xa.w, xc.x, xc.y, xc.z};

  const float* w0 = W0g + l * (IN_DIM * C0);
  const float* B0 = b0g + l * C0;
  const float* w1 = W1g + l * (C0 * C1);
  const float* B1 = b1g + l * C1;

  float h[C0];
#pragma unroll
  for (int c = 0; c < C0; c++) h[c] = B0[c];
#pragma unroll
  for (int k = 0; k < IN_DIM; k++)
#pragma unroll
    for (int c = 0; c < C0; c++) h[c] = fmaf(x[k], w0[k * C0 + c], h[c]);
#pragma unroll
  for (int c = 0; c < C0; c++) h[c] = h[c] >= 0.f ? h[c] : 0.2f * h[c];

  float o[C1];
#pragma unroll
  for (int c = 0; c < C1; c++) o[c] = B1[c];
#pragma unroll
  for (int k = 0; k < C0; k++)
#pragma unroll
    for (int c = 0; c < C1; c++) o[c] = fmaf(h[k], w1[k * C1 + c], o[c]);
#pragma unroll
  for (int c = 0; c < C1; c++) o[c] = o[c] >= 0.f ? o[c] : 0.2f * o[c];

  __shared__ float obuf[4 * 64 * 32];
  float* tile = &obuf[(T >> 6) * (64 * 32)];
#pragma unroll
  for (int cq = 0; cq < 32; cq += 4) {
    int ad = lane * 32 + (cq ^ ((lane & 7) << 2));
    float4 v = {o[cq], o[cq + 1], o[cq + 2], o[cq + 3]};
    *(float4*)&tile[ad] = v;
  }
  int wavebase = blockbase + (T >> 6) * 64;
  int q = (lane & 7) * 4;
  int rbase = lane >> 3;
#pragma unroll
  for (int step = 0; step < 8; step++) {
    int row = step * 8 + rbase;
    int slot_r = wavebase + row;
    if (slot_r < end) {
      int p = perm[slot_r];
      int sw = (row & 7) << 2;
      float4 v = *(const float4*)&tile[row * 32 + (q ^ sw)];
      *(float4*)(out + (size_t)p * C1 + q) = v;
    }
  }
}

// ======================= DIAGNOSTIC ABLATIONS (write ws only) =================
// Shared body macro'd by hand; each at 2x grid (blockbase wraps mod nBlk).

// V2: full body + epilogue reads, NO global stores (keepalive).
__global__ __launch_bounds__(256) void k_diag_nostore(const float* __restrict__ xb,
                                                      const float* __restrict__ W0g,
                                                      const float* __restrict__ b0g,
                                                      const float* __restrict__ W1g,
                                                      const float* __restrict__ b1g,
                                                      const int* __restrict__ perm,
                                                      const int* __restrict__ baseArr,
                                                      const int* __restrict__ endArr,
                                                      int nBlk) {
  int T = threadIdx.x;
  int lane = T & 63;
  int blockbase = (blockIdx.x % nBlk) << 8;
  int bv = baseArr[lane <= L ? lane : L];
  unsigned long long m = __ballot((lane <= L) && (blockbase >= bv));
  int l = __popcll(m) - 1;
  if (l >= L) return;
  l = __builtin_amdgcn_readfirstlane(l);
  int end = __builtin_amdgcn_readfirstlane(endArr[l]);

  int slot = blockbase + T;
  const float4* xrow = (const float4*)(xb + (size_t)slot * 8);
  float4 xa = xrow[0], xc = xrow[1];
  float x[IN_DIM] = {xa.x, xa.y, xa.z, xa.w, xc.x, xc.y, xc.z};

  const float* w0 = W0g + l * (IN_DIM * C0);
  const float* B0 = b0g + l * C0;
  const float* w1 = W1g + l * (C0 * C1);
  const float* B1 = b1g + l * C1;

  float h[C0];
#pragma unroll
  for (int c = 0; c < C0; c++) h[c] = B0[c];
#pragma unroll
  for (int k = 0; k < IN_DIM; k++)
#pragma unroll
    for (int c = 0; c < C0; c++) h[c] = fmaf(x[k], w0[k * C0 + c], h[c]);
#pragma unroll
  for (int c = 0; c < C0; c++) h[c] = h[c] >= 0.f ? h[c] : 0.2f * h[c];
  float o[C1];
#pragma unroll
  for (int c = 0; c < C1; c++) o[c] = B1[c];
#pragma unroll
  for (int k = 0; k < C0; k++)
#pragma unroll
    for (int c = 0; c < C1; c++) o[c] = fmaf(h[k], w1[k * C1 + c], o[c]);
#pragma unroll
  for (int c = 0; c < C1; c++) o[c] = o[c] >= 0.f ? o[c] : 0.2f * o[c];

  __shared__ float obuf[4 * 64 * 32];
  float* tile = &obuf[(T >> 6) * (64 * 32)];
#pragma unroll
  for (int cq = 0; cq < 32; cq += 4) {
    int ad = lane * 32 + (cq ^ ((lane & 7) << 2));
    float4 v = {o[cq], o[cq + 1], o[cq + 2], o[cq + 3]};
    *(float4*)&tile[ad] = v;
  }
  int wavebase = blockbase + (T >> 6) * 64;
  int q = (lane & 7) * 4;
  int rbase = lane >> 3;
#pragma unroll
  for (int step = 0; step < 8; step++) {
    int row = step * 8 + rbase;
    int slot_r = wavebase + row;
    if (slot_r < end) {
      int p = perm[slot_r];
      int sw = (row & 7) << 2;
      float4 v = *(const float4*)&tile[row * 32 + (q ^ sw)];
      asm volatile("" :: "v"(v.x), "v"(v.y), "v"(v.z), "v"(v.w), "v"(p));  // no store
    }
  }
}

// V3: weights replaced by 8 preloaded regs; scattered stores into ws scratch.
__global__ __launch_bounds__(256) void k_diag_noweights(const float* __restrict__ xb,
                                                        const float* __restrict__ W0g,
                                                        const int* __restrict__ perm,
                                                        const int* __restrict__ baseArr,
                                                        const int* __restrict__ endArr,
                                                        float* __restrict__ scratch,
                                                        int nBlk) {
  int T = threadIdx.x;
  int lane = T & 63;
  int blockbase = (blockIdx.x % nBlk) << 8;
  int bv = baseArr[lane <= L ? lane : L];
  unsigned long long m = __ballot((lane <= L) && (blockbase >= bv));
  int l = __popcll(m) - 1;
  if (l >= L) return;
  l = __builtin_amdgcn_readfirstlane(l);
  int end = __builtin_amdgcn_readfirstlane(endArr[l]);

  int slot = blockbase + T;
  const float4* xrow = (const float4*)(xb + (size_t)slot * 8);
  float4 xa = xrow[0], xc = xrow[1];
  float x[IN_DIM] = {xa.x, xa.y, xa.z, xa.w, xc.x, xc.y, xc.z};

  float wk8[8];
#pragma unroll
  for (int j = 0; j < 8; j++) wk8[j] = W0g[j];  // one s_load group, K$-trivial

  float h[C0];
#pragma unroll
  for (int c = 0; c < C0; c++) h[c] = wk8[c & 7];
#pragma unroll
  for (int k = 0; k < IN_DIM; k++)
#pragma unroll
    for (int c = 0; c < C0; c++) h[c] = fmaf(x[k], wk8[(k + c) & 7], h[c]);
#pragma unroll
  for (int c = 0; c < C0; c++) h[c] = h[c] >= 0.f ? h[c] : 0.2f * h[c];
  float o[C1];
#pragma unroll
  for (int c = 0; c < C1; c++) o[c] = wk8[c & 7];
#pragma unroll
  for (int k = 0; k < C0; k++)
#pragma unroll
    for (int c = 0; c < C1; c++) o[c] = fmaf(h[k], wk8[(k + c) & 7], o[c]);
#pragma unroll
  for (int c = 0; c < C1; c++) o[c] = o[c] >= 0.f ? o[c] : 0.2f * o[c];

  __shared__ float obuf[4 * 64 * 32];
  float* tile = &obuf[(T >> 6) * (64 * 32)];
#pragma unroll
  for (int cq = 0; cq < 32; cq += 4) {
    int ad = lane * 32 + (cq ^ ((lane & 7) << 2));
    float4 v = {o[cq], o[cq + 1], o[cq + 2], o[cq + 3]};
    *(float4*)&tile[ad] = v;
  }
  int wavebase = blockbase + (T >> 6) * 64;
  int q = (lane & 7) * 4;
  int rbase = lane >> 3;
#pragma unroll
  for (int step = 0; step < 8; step++) {
    int row = step * 8 + rbase;
    int slot_r = wavebase + row;
    if (slot_r < end) {
      int p = perm[slot_r];
      int sw = (row & 7) << 2;
      float4 v = *(const float4*)&tile[row * 32 + (q ^ sw)];
      *(float4*)(scratch + (size_t)p * C1 + q) = v;  // same scatter pattern
    }
  }
}

// V4: pure body floor -- no xb, no weight stream, no stores. Instruction
// stream + VALU + LDS epilogue only.
__global__ __launch_bounds__(256) void k_diag_bodyonly(const float* __restrict__ W0g,
                                                       const int* __restrict__ baseArr,
                                                       const int* __restrict__ endArr,
                                                       int nBlk) {
  int T = threadIdx.x;
  int lane = T & 63;
  int blockbase = (blockIdx.x % nBlk) << 8;
  int bv = baseArr[lane <= L ? lane : L];
  unsigned long long m = __ballot((lane <= L) && (blockbase >= bv));
  int l = __popcll(m) - 1;
  if (l >= L) return;
  l = __builtin_amdgcn_readfirstlane(l);
  int end = __builtin_amdgcn_readfirstlane(endArr[l]);

  int seed = T;
  asm volatile("" : "+v"(seed));  // opaque: block constant folding
  float x[IN_DIM];
#pragma unroll
  for (int k = 0; k < IN_DIM; k++) x[k] = (float)((seed >> k) & 7);

  float wk8[8];
#pragma unroll
  for (int j = 0; j < 8; j++) wk8[j] = W0g[j];

  float h[C0];
#pragma unroll
  for (int c = 0; c < C0; c++) h[c] = wk8[c & 7];
#pragma unroll
  for (int k = 0; k < IN_DIM; k++)
#pragma unroll
    for (int c = 0; c < C0; c++) h[c] = fmaf(x[k], wk8[(k + c) & 7], h[c]);
#pragma unroll
  for (int c = 0; c < C0; c++) h[c] = h[c] >= 0.f ? h[c] : 0.2f * h[c];
  float o[C1];
#pragma unroll
  for (int c = 0; c < C1; c++) o[c] = wk8[c & 7];
#pragma unroll
  for (int k = 0; k < C0; k++)
#pragma unroll
    for (int c = 0; c < C1; c++) o[c] = fmaf(h[k], wk8[(k + c) & 7], o[c]);
#pragma unroll
  for (int c = 0; c < C1; c++) o[c] = o[c] >= 0.f ? o[c] : 0.2f * o[c];

  __shared__ float obuf[4 * 64 * 32];
  float* tile = &obuf[(T >> 6) * (64 * 32)];
#pragma unroll
  for (int cq = 0; cq < 32; cq += 4) {
    int ad = lane * 32 + (cq ^ ((lane & 7) << 2));
    float4 v = {o[cq], o[cq + 1], o[cq + 2], o[cq + 3]};
    *(float4*)&tile[ad] = v;
  }
  int q = (lane & 7) * 4;
  int rbase = lane >> 3;
#pragma unroll
  for (int step = 0; step < 8; step++) {
    int row = step * 8 + rbase;
    int sw = (row & 7) << 2;
    float4 v = *(const float4*)&tile[row * 32 + (q ^ sw)];
    if (row < end)  // always true in practice; keeps the branch structure
      asm volatile("" :: "v"(v.x), "v"(v.y), "v"(v.z), "v"(v.w));
  }
}

extern "C" void kernel_launch(void* const* d_in, const int* in_sizes, int n_in,
                              void* d_out, int out_size, void* d_ws, size_t ws_size,
                              hipStream_t stream) {
  const float* inp = (const float*)d_in[0];
  const int* idx   = (const int*)d_in[1];
  const float* W0  = (const float*)d_in[2];
  const float* b0  = (const float*)d_in[3];
  const float* W1  = (const float*)d_in[4];
  const float* b1  = (const float*)d_in[5];
  float* out = (float*)d_out;
  int E = in_sizes[1];

  int nBlk = (E + 255) / 256 + L;
  size_t slots = (size_t)nBlk * 256;

  int* ws = (int*)d_ws;
  int* blockCounts = ws;                       // GHIST*L
  int* cursor      = blockCounts + GHIST * L;  // GHIST*L
  int* endArr      = cursor + GHIST * L;       // L
  int* baseArr     = endArr + L;               // L+1
  int* perm        = baseArr + (L + 1);        // slots
  size_t ints = (size_t)2 * GHIST * L + L + (L + 1) + slots;
  ints = (ints + 3) & ~(size_t)3;
  float* xb = (float*)(ws + ints);             // slots * 8 floats
  float* scratch = xb + slots * 8;             // slots * 32 floats (diag)
  size_t need1 = ints * 4 + slots * 8 * 4;
  size_t need2 = need1 + slots * 32 * 4;

  k_hist<<<GHIST, 256, 0, stream>>>(idx, E, blockCounts);
  k_scan<<<1, 256, 0, stream>>>(blockCounts, cursor, endArr, baseArr);
  k_scatter<<<GHIST, 256, 0, stream>>>(idx, inp, E, cursor, perm, xb);

  // production output
  k_compute<<<nBlk, 256, 0, stream>>>(xb, W0, b0, W1, b1,
                                      perm, baseArr, endArr, out);

  // diagnostics at 2x grid (visible in top-5 iff 1x-cost >= ~38us)
  if (ws_size >= need2) {
    k_diag_nostore<<<nBlk * 2, 256, 0, stream>>>(xb, W0, b0, W1, b1,
                                                 perm, baseArr, endArr, nBlk);
    k_diag_noweights<<<nBlk * 2, 256, 0, stream>>>(xb, W0, perm, baseArr, endArr,
                                                   scratch, nBlk);
    k_diag_bodyonly<<<nBlk * 2, 256, 0, stream>>>(W0, baseArr, endArr, nBlk);
  }
}